// Round 4
// baseline (1665.429 us; speedup 1.0000x reference)
//
#include <hip/hip_runtime.h>
#include <math.h>

#define H 256
#define G3 768        // 3*H
#define BB 512
#define AA 4
#define EE 10
#define RP (BB*AA*EE) // 20480 physical rows
#define RA (BB*AA)    // 2048 action rows
#define TT 10
#define NMV 2
#define STEPSC 0.05f

typedef __attribute__((ext_vector_type(8))) short short8;
typedef __attribute__((ext_vector_type(4))) float f32x4;
typedef unsigned short ushort_t;

__device__ __forceinline__ float sigmoid_(float x){ return 1.f/(1.f + __expf(-x)); }
__device__ __forceinline__ float tanh_(float x){
    float ax = fabsf(x);
    float e  = __expf(-2.f*ax);
    float t  = (1.f - e)/(1.f + e);
    return copysignf(t, x);
}
__device__ __forceinline__ float elu_(float x){ return x > 0.f ? x : (__expf(x) - 1.f); }

__device__ __forceinline__ ushort_t f2bf(float x){
    union { float f; unsigned int u; } v; v.f = x;
    unsigned int r = v.u + 0x7fffu + ((v.u >> 16) & 1u);
    return (ushort_t)(r >> 16);
}
__device__ __forceinline__ float bf2f(ushort_t b){
    union { unsigned int u; float f; } v; v.u = ((unsigned int)b) << 16; return v.f;
}

// ---------------------------------------------------------------------------
// split fp32 -> (hi, lo) bf16 pair, linear layout (states)
// ---------------------------------------------------------------------------
__global__ void k_split(const float* __restrict__ src,
                        ushort_t* __restrict__ hi, ushort_t* __restrict__ lo, int n)
{
    int i = blockIdx.x*256 + threadIdx.x;
    if (i < n) {
        float x = src[i];
        ushort_t h = f2bf(x);
        hi[i] = h;
        lo[i] = f2bf(x - bf2f(h));
    }
}

// ---------------------------------------------------------------------------
// split fp32 weight [N][ldsrc] -> MFMA B-fragment-ordered hi/lo bf16 buffers.
// Frag order: i = ((chunk*8 + kc)*64 + lane)*8 + j
//   row(outcol) = chunk*16 + (lane&15), k = kc*32 + (lane>>4)*8 + j
// A wave reading (chunk,kc) at lane*8 gets 64x16B fully contiguous.
// ---------------------------------------------------------------------------
__global__ void k_split_frag(const float* __restrict__ src,
                             ushort_t* __restrict__ hi, ushort_t* __restrict__ lo,
                             int n, int ldsrc)
{
    int i = blockIdx.x*256 + threadIdx.x;
    if (i < n) {
        int j  = i & 7;
        int l  = (i >> 3) & 63;
        int kc = (i >> 9) & 7;
        int c  = i >> 12;
        int row = c*16 + (l & 15);
        int k   = kc*32 + (l >> 4)*8 + j;
        float x = src[(size_t)row*ldsrc + k];
        ushort_t h = f2bf(x);
        hi[i] = h;
        lo[i] = f2bf(x - bf2f(h));
    }
}

// gia_goal[ra][k] = b_ih_a[k] + sum_{j<3} goals[ra][j]*W_ih_a[k][256+j]
__global__ void k_gia_goal(const float* __restrict__ goals,
                           const float* __restrict__ Wiha,
                           const float* __restrict__ biha,
                           float* __restrict__ out)
{
    int idx = blockIdx.x*256 + threadIdx.x;
    int ra = idx / G3, k = idx % G3;
    float g0 = goals[ra*3+0], g1 = goals[ra*3+1], g2 = goals[ra*3+2];
    const float* w = Wiha + (size_t)k*259 + 256;
    out[idx] = biha[k] + g0*w[0] + g1*w[1] + g2*w[2];
}

// ---------------------------------------------------------------------------
// MFMA GRU, v3: A-in-registers across NS col-slices, fragment-ordered weights
// staged via LDS (conflict-free contiguous reads), single 48 KB buffer.
// Block 256 thr = 4 waves x 32 rows = 128 rows. grid=(M/128, 16/NS).
// Per slice: 16 cols x 3 gates; K-loop pure LDS+MFMA (x3 split-bf16).
// ---------------------------------------------------------------------------
template<int NS, int INLINE_GI>
__global__ __launch_bounds__(256, 2)
void k_gru3(const ushort_t* __restrict__ h_hi, const ushort_t* __restrict__ h_lo,
            ushort_t* __restrict__ o_hi, ushort_t* __restrict__ o_lo,
            const ushort_t* __restrict__ wf_hi, const ushort_t* __restrict__ wf_lo,
            const float* __restrict__ gi,
            const float* __restrict__ obs, const float* __restrict__ phys,
            const float* __restrict__ Wih, const float* __restrict__ bih,
            const float* __restrict__ bhh)
{
    __shared__ ushort_t Bh[48*256];   // 24 KB: 3 chunks of (8 kc x 64 lane x 8)
    __shared__ ushort_t Bl[48*256];   // 24 KB

    const int tid = threadIdx.x;
    const int wv = tid >> 6, lane = tid & 63;
    const int quad = lane >> 4, l16 = lane & 15;
    const int m0 = blockIdx.x*128 + wv*32;

    // --- A preload: 32 rows/wave, full K, hi+lo (128 VGPR) ---
    const size_t a0 = (size_t)(m0 + l16)*H + quad*8;
    const size_t a1 = a0 + (size_t)16*H;
    short8 Ah[2][8], Al[2][8];
    #pragma unroll
    for (int kc = 0; kc < 8; kc++) {
        Ah[0][kc] = *(const short8*)(h_hi + a0 + kc*32);
        Al[0][kc] = *(const short8*)(h_lo + a0 + kc*32);
        Ah[1][kc] = *(const short8*)(h_hi + a1 + kc*32);
        Al[1][kc] = *(const short8*)(h_lo + a1 + kc*32);
    }

    for (int s = 0; s < NS; s++) {
        const int cs = blockIdx.y*NS + s;     // col-slice 0..15
        // --- stage B slice: chunks {g*16+cs} for g=0..2, linear copy ---
        #pragma unroll
        for (int g = 0; g < 3; g++) {
            const size_t csrc = (size_t)(g*16 + cs)*4096;
            *(short8*)&Bh[g*4096 + tid*8]        = *(const short8*)(wf_hi + csrc + tid*8);
            *(short8*)&Bh[g*4096 + 2048 + tid*8] = *(const short8*)(wf_hi + csrc + 2048 + tid*8);
            *(short8*)&Bl[g*4096 + tid*8]        = *(const short8*)(wf_lo + csrc + tid*8);
            *(short8*)&Bl[g*4096 + 2048 + tid*8] = *(const short8*)(wf_lo + csrc + 2048 + tid*8);
        }
        __syncthreads();

        f32x4 acc[3][2];
        #pragma unroll
        for (int g = 0; g < 3; g++)
            #pragma unroll
            for (int mi = 0; mi < 2; mi++)
                acc[g][mi] = (f32x4){0.f,0.f,0.f,0.f};

        #pragma unroll
        for (int kc = 0; kc < 8; kc++) {
            #pragma unroll
            for (int g = 0; g < 3; g++) {
                short8 bh = *(const short8*)&Bh[g*4096 + kc*512 + lane*8];
                short8 bl = *(const short8*)&Bl[g*4096 + kc*512 + lane*8];
                acc[g][0] = __builtin_amdgcn_mfma_f32_16x16x32_bf16(Ah[0][kc], bh, acc[g][0], 0,0,0);
                acc[g][0] = __builtin_amdgcn_mfma_f32_16x16x32_bf16(Al[0][kc], bh, acc[g][0], 0,0,0);
                acc[g][0] = __builtin_amdgcn_mfma_f32_16x16x32_bf16(Ah[0][kc], bl, acc[g][0], 0,0,0);
                acc[g][1] = __builtin_amdgcn_mfma_f32_16x16x32_bf16(Ah[1][kc], bh, acc[g][1], 0,0,0);
                acc[g][1] = __builtin_amdgcn_mfma_f32_16x16x32_bf16(Al[1][kc], bh, acc[g][1], 0,0,0);
                acc[g][1] = __builtin_amdgcn_mfma_f32_16x16x32_bf16(Ah[1][kc], bl, acc[g][1], 0,0,0);
            }
        }

        // --- epilogue for this slice ---
        const int col = cs*16 + l16;
        float wr[5], wz[5], wn[5], br_=0, bz_=0, bn_=0;
        if (INLINE_GI) {
            const float* pr = Wih + (size_t)col*5;
            const float* pz = Wih + (size_t)(256+col)*5;
            const float* pn = Wih + (size_t)(512+col)*5;
            #pragma unroll
            for (int j = 0; j < 5; j++) { wr[j]=pr[j]; wz[j]=pz[j]; wn[j]=pn[j]; }
            br_ = bih[col]; bz_ = bih[256+col]; bn_ = bih[512+col];
        }
        const float bhr = bhh[col], bhz = bhh[256+col], bhn = bhh[512+col];
        #pragma unroll
        for (int mi = 0; mi < 2; mi++) {
            #pragma unroll
            for (int r = 0; r < 4; r++) {
                int row = m0 + mi*16 + quad*4 + r;
                float gr, gz, gn;
                if (INLINE_GI) {
                    float x0 = obs[(size_t)row*2+0];
                    float x1 = obs[(size_t)row*2+1];
                    int b = row / (AA*EE);
                    int e = row % EE;
                    const float* pp = phys + (size_t)(b*EE + e)*3;
                    float x2 = pp[0], x3 = pp[1], x4 = pp[2];
                    gr = br_; gz = bz_; gn = bn_;
                    gr = fmaf(x0,wr[0],gr); gr = fmaf(x1,wr[1],gr); gr = fmaf(x2,wr[2],gr);
                    gr = fmaf(x3,wr[3],gr); gr = fmaf(x4,wr[4],gr);
                    gz = fmaf(x0,wz[0],gz); gz = fmaf(x1,wz[1],gz); gz = fmaf(x2,wz[2],gz);
                    gz = fmaf(x3,wz[3],gz); gz = fmaf(x4,wz[4],gz);
                    gn = fmaf(x0,wn[0],gn); gn = fmaf(x1,wn[1],gn); gn = fmaf(x2,wn[2],gn);
                    gn = fmaf(x3,wn[3],gn); gn = fmaf(x4,wn[4],gn);
                } else {
                    const float* gp = gi + (size_t)row*G3;
                    gr = gp[col]; gz = gp[256+col]; gn = gp[512+col];
                }
                float hr = acc[0][mi][r] + bhr;
                float hz = acc[1][mi][r] + bhz;
                float hn = acc[2][mi][r] + bhn;
                float rg = sigmoid_(gr + hr);
                float z  = sigmoid_(gz + hz);
                float n  = tanh_(gn + rg*hn);
                size_t idx = (size_t)row*H + col;
                float hprev = bf2f(h_hi[idx]) + bf2f(h_lo[idx]);
                float h = (1.f - z)*n + z*hprev;
                ushort_t hb = f2bf(h);
                o_hi[idx] = hb;
                o_lo[idx] = f2bf(h - bf2f(hb));
            }
        }
        if (s + 1 < NS) __syncthreads();   // protect LDS before re-stage
    }
}

// ---------------------------------------------------------------------------
// MFMA FC, v3: same structure; 32-col slices (2 chunks). grid=(M/128, (N/32)/NS).
// MODE 0: split(elu(acc+bias)) -> o_hi/o_lo ; MODE 1: f32 acc + Cin -> o_f32
// ---------------------------------------------------------------------------
template<int NS, int MODE>
__global__ __launch_bounds__(256, 2)
void k_fc3(const ushort_t* __restrict__ h_hi, const ushort_t* __restrict__ h_lo,
           const ushort_t* __restrict__ wf_hi, const ushort_t* __restrict__ wf_lo,
           const float* __restrict__ bias, const float* __restrict__ Cin, int N,
           ushort_t* __restrict__ o_hi, ushort_t* __restrict__ o_lo,
           float* __restrict__ o_f32)
{
    __shared__ ushort_t Bh[2*4096];   // 16 KB (2 chunks)
    __shared__ ushort_t Bl[2*4096];

    const int tid = threadIdx.x;
    const int wv = tid >> 6, lane = tid & 63;
    const int quad = lane >> 4, l16 = lane & 15;
    const int m0 = blockIdx.x*128 + wv*32;

    const size_t a0 = (size_t)(m0 + l16)*H + quad*8;
    const size_t a1 = a0 + (size_t)16*H;
    short8 Ah[2][8], Al[2][8];
    #pragma unroll
    for (int kc = 0; kc < 8; kc++) {
        Ah[0][kc] = *(const short8*)(h_hi + a0 + kc*32);
        Al[0][kc] = *(const short8*)(h_lo + a0 + kc*32);
        Ah[1][kc] = *(const short8*)(h_hi + a1 + kc*32);
        Al[1][kc] = *(const short8*)(h_lo + a1 + kc*32);
    }

    for (int s = 0; s < NS; s++) {
        const int cs = blockIdx.y*NS + s;       // 32-col slice index
        const size_t csrc = (size_t)cs*8192;    // 2 contiguous chunks
        #pragma unroll
        for (int i = 0; i < 4; i++) {
            *(short8*)&Bh[i*2048 + tid*8] = *(const short8*)(wf_hi + csrc + i*2048 + tid*8);
            *(short8*)&Bl[i*2048 + tid*8] = *(const short8*)(wf_lo + csrc + i*2048 + tid*8);
        }
        __syncthreads();

        f32x4 acc[2][2];
        #pragma unroll
        for (int mi = 0; mi < 2; mi++)
            #pragma unroll
            for (int ni = 0; ni < 2; ni++)
                acc[mi][ni] = (f32x4){0.f,0.f,0.f,0.f};

        #pragma unroll
        for (int kc = 0; kc < 8; kc++) {
            #pragma unroll
            for (int ni = 0; ni < 2; ni++) {
                short8 bh = *(const short8*)&Bh[ni*4096 + kc*512 + lane*8];
                short8 bl = *(const short8*)&Bl[ni*4096 + kc*512 + lane*8];
                acc[0][ni] = __builtin_amdgcn_mfma_f32_16x16x32_bf16(Ah[0][kc], bh, acc[0][ni], 0,0,0);
                acc[0][ni] = __builtin_amdgcn_mfma_f32_16x16x32_bf16(Al[0][kc], bh, acc[0][ni], 0,0,0);
                acc[0][ni] = __builtin_amdgcn_mfma_f32_16x16x32_bf16(Ah[0][kc], bl, acc[0][ni], 0,0,0);
                acc[1][ni] = __builtin_amdgcn_mfma_f32_16x16x32_bf16(Ah[1][kc], bh, acc[1][ni], 0,0,0);
                acc[1][ni] = __builtin_amdgcn_mfma_f32_16x16x32_bf16(Al[1][kc], bh, acc[1][ni], 0,0,0);
                acc[1][ni] = __builtin_amdgcn_mfma_f32_16x16x32_bf16(Ah[1][kc], bl, acc[1][ni], 0,0,0);
            }
        }

        #pragma unroll
        for (int mi = 0; mi < 2; mi++) {
            #pragma unroll
            for (int r = 0; r < 4; r++) {
                int row = m0 + mi*16 + quad*4 + r;
                #pragma unroll
                for (int ni = 0; ni < 2; ni++) {
                    int colg = cs*32 + ni*16 + l16;
                    size_t idx = (size_t)row*N + colg;
                    float v = acc[mi][ni][r];
                    if (MODE == 0) {
                        v = elu_(v + bias[colg]);
                        ushort_t hb = f2bf(v);
                        o_hi[idx] = hb;
                        o_lo[idx] = f2bf(v - bf2f(hb));
                    } else {
                        o_f32[idx] = v + Cin[idx];
                    }
                }
            }
        }
        if (s + 1 < NS) __syncthreads();
    }
}

// feat[ba][j] = max_e (proc_hi+proc_lo), output split
__global__ void k_pool2(const ushort_t* __restrict__ p_hi, const ushort_t* __restrict__ p_lo,
                        ushort_t* __restrict__ f_hi, ushort_t* __restrict__ f_lo)
{
    int idx = blockIdx.x*256 + threadIdx.x;   // RA*H
    int ba = idx >> 8, j = idx & 255;
    size_t base = (size_t)ba*EE*H + j;
    float m = bf2f(p_hi[base]) + bf2f(p_lo[base]);
    #pragma unroll
    for (int e = 1; e < EE; e++) {
        float v = bf2f(p_hi[base + (size_t)e*H]) + bf2f(p_lo[base + (size_t)e*H]);
        m = fmaxf(m, v);
    }
    ushort_t hb = f2bf(m);
    f_hi[idx] = hb;
    f_lo[idx] = f2bf(m - bf2f(hb));
}

// out[row][v] = tanh(b_m2[v] + (m1_hi+m1_lo)[row] . W_m2[v]) * STEP
__global__ void k_m2(const ushort_t* __restrict__ xh, const ushort_t* __restrict__ xl,
                     const float* __restrict__ Wm2, const float* __restrict__ bm2,
                     float* __restrict__ out)
{
    int idx = blockIdx.x*256 + threadIdx.x;   // RA*NMV
    int row = idx >> 1, v = idx & 1;
    const short8* ph = (const short8*)(xh + (size_t)row*H);
    const short8* pl = (const short8*)(xl + (size_t)row*H);
    const float* w = Wm2 + (size_t)v*H;
    float s = bm2[v];
    #pragma unroll 4
    for (int i = 0; i < H/8; i++) {
        short8 a = ph[i], b = pl[i];
        #pragma unroll
        for (int j = 0; j < 8; j++) {
            float x = bf2f((ushort_t)a[j]) + bf2f((ushort_t)b[j]);
            s = fmaf(x, w[i*8+j], s);
        }
    }
    out[idx] = tanh_(s) * STEPSC;
}

extern "C" void kernel_launch(void* const* d_in, const int* in_sizes, int n_in,
                              void* d_out, int out_size, void* d_ws, size_t ws_size,
                              hipStream_t stream)
{
    const float* obs  = (const float*)d_in[0];
    const float* phys = (const float*)d_in[1];
    const float* goals= (const float*)d_in[2];
    const float* memp = (const float*)d_in[3];
    const float* mema = (const float*)d_in[4];
    const float* Wihp = (const float*)d_in[5];
    const float* Whhp = (const float*)d_in[6];
    const float* bihp = (const float*)d_in[7];
    const float* bhhp = (const float*)d_in[8];
    const float* Wfcp = (const float*)d_in[9];
    const float* bfcp = (const float*)d_in[10];
    const float* Wiha = (const float*)d_in[11];
    const float* Whha = (const float*)d_in[12];
    const float* biha = (const float*)d_in[13];
    const float* bhha = (const float*)d_in[14];
    const float* Wfca = (const float*)d_in[15];
    const float* bfca = (const float*)d_in[16];
    const float* Wm1  = (const float*)d_in[17];
    const float* bm1  = (const float*)d_in[18];
    const float* Wm2  = (const float*)d_in[19];
    const float* bm2  = (const float*)d_in[20];
    float* out = (float*)d_out;

    char* base = (char*)d_ws;
    size_t off = 0;
    auto alloc = [&](size_t bytes) -> char* {
        char* p = base + off;
        off += (bytes + 255) & ~(size_t)255;
        return p;
    };
    ushort_t* whh_hi  = (ushort_t*)alloc((size_t)G3*H*2);
    ushort_t* whh_lo  = (ushort_t*)alloc((size_t)G3*H*2);
    ushort_t* wfc_hi  = (ushort_t*)alloc((size_t)H*H*2);
    ushort_t* wfc_lo  = (ushort_t*)alloc((size_t)H*H*2);
    ushort_t* whha_hi = (ushort_t*)alloc((size_t)G3*H*2);
    ushort_t* whha_lo = (ushort_t*)alloc((size_t)G3*H*2);
    ushort_t* wiha_hi = (ushort_t*)alloc((size_t)G3*H*2);
    ushort_t* wiha_lo = (ushort_t*)alloc((size_t)G3*H*2);
    ushort_t* wfca_hi = (ushort_t*)alloc((size_t)H*H*2);
    ushort_t* wfca_lo = (ushort_t*)alloc((size_t)H*H*2);
    ushort_t* wm1_hi  = (ushort_t*)alloc((size_t)H*H*2);
    ushort_t* wm1_lo  = (ushort_t*)alloc((size_t)H*H*2);
    ushort_t* hpA_hi  = (ushort_t*)alloc((size_t)RP*H*2);
    ushort_t* hpA_lo  = (ushort_t*)alloc((size_t)RP*H*2);
    ushort_t* hpB_hi  = (ushort_t*)alloc((size_t)RP*H*2);
    ushort_t* hpB_lo  = (ushort_t*)alloc((size_t)RP*H*2);
    ushort_t* haA_hi  = (ushort_t*)alloc((size_t)RA*H*2);
    ushort_t* haA_lo  = (ushort_t*)alloc((size_t)RA*H*2);
    ushort_t* haB_hi  = (ushort_t*)alloc((size_t)RA*H*2);
    ushort_t* haB_lo  = (ushort_t*)alloc((size_t)RA*H*2);
    ushort_t* proc_hi = (ushort_t*)alloc((size_t)RP*H*2);
    ushort_t* proc_lo = (ushort_t*)alloc((size_t)RP*H*2);
    ushort_t* feat_hi = (ushort_t*)alloc((size_t)RA*H*2);
    ushort_t* feat_lo = (ushort_t*)alloc((size_t)RA*H*2);
    float* gia_goal   = (float*)alloc((size_t)RA*G3*4);
    float* gi_a       = (float*)alloc((size_t)RA*G3*4);
    // transient action tensors alias the (dead-at-that-point) proc region
    ushort_t* proca_hi = proc_hi;
    ushort_t* proca_lo = proc_hi + (size_t)RA*H;
    ushort_t* m1o_hi   = proc_hi + (size_t)2*RA*H;
    ushort_t* m1o_lo   = proc_hi + (size_t)3*RA*H;

    // --- pre-pass: split weights (fragment order) and states (linear) ---
    k_split_frag<<<(G3*H+255)/256, 256, 0, stream>>>(Whhp, whh_hi, whh_lo, G3*H, H);
    k_split_frag<<<(H*H+255)/256, 256, 0, stream>>>(Wfcp, wfc_hi, wfc_lo, H*H, H);
    k_split_frag<<<(G3*H+255)/256, 256, 0, stream>>>(Whha, whha_hi, whha_lo, G3*H, H);
    k_split_frag<<<(G3*H+255)/256, 256, 0, stream>>>(Wiha, wiha_hi, wiha_lo, G3*H, 259);
    k_split_frag<<<(H*H+255)/256, 256, 0, stream>>>(Wfca, wfca_hi, wfca_lo, H*H, H);
    k_split_frag<<<(H*H+255)/256, 256, 0, stream>>>(Wm1, wm1_hi, wm1_lo, H*H, H);
    k_split<<<((size_t)RP*H+255)/256, 256, 0, stream>>>(memp, hpA_hi, hpA_lo, RP*H);
    k_split<<<((size_t)RA*H+255)/256, 256, 0, stream>>>(mema, haA_hi, haA_lo, RA*H);
    k_gia_goal<<<RA*G3/256, 256, 0, stream>>>(goals, Wiha, biha, gia_goal);

    ushort_t *pi_h = hpA_hi, *pi_l = hpA_lo, *po_h = hpB_hi, *po_l = hpB_lo;
    ushort_t *ai_h = haA_hi, *ai_l = haA_lo, *ao_h = haB_hi, *ao_l = haB_lo;
    for (int t = 0; t < TT; t++) {
        // physical chain
        k_gru3<4,1><<<dim3(RP/128, 4), 256, 0, stream>>>(pi_h, pi_l, po_h, po_l,
                                                         whh_hi, whh_lo, nullptr,
                                                         obs, phys, Wihp, bihp, bhhp);
        k_fc3<2,0><<<dim3(RP/128, 4), 256, 0, stream>>>(po_h, po_l, wfc_hi, wfc_lo,
                                                        bfcp, nullptr, H, proc_hi, proc_lo, nullptr);
        k_pool2<<<RA*H/256, 256, 0, stream>>>(proc_hi, proc_lo, feat_hi, feat_lo);
        // action chain
        k_fc3<1,1><<<dim3(RA/128, 24), 256, 0, stream>>>(feat_hi, feat_lo, wiha_hi, wiha_lo,
                                                         nullptr, gia_goal, G3, nullptr, nullptr, gi_a);
        k_gru3<1,0><<<dim3(RA/128, 16), 256, 0, stream>>>(ai_h, ai_l, ao_h, ao_l,
                                                          whha_hi, whha_lo, gi_a,
                                                          nullptr, nullptr, nullptr, nullptr, bhha);
        k_fc3<1,0><<<dim3(RA/128, 8), 256, 0, stream>>>(ao_h, ao_l, wfca_hi, wfca_lo,
                                                        bfca, nullptr, H, proca_hi, proca_lo, nullptr);
        k_fc3<1,0><<<dim3(RA/128, 8), 256, 0, stream>>>(proca_hi, proca_lo, wm1_hi, wm1_lo,
                                                        bm1, nullptr, H, m1o_hi, m1o_lo, nullptr);
        k_m2<<<RA*NMV/256, 256, 0, stream>>>(m1o_hi, m1o_lo, Wm2, bm2, out + (size_t)t*RA*NMV);

        ushort_t* ts;
        ts = pi_h; pi_h = po_h; po_h = ts;
        ts = pi_l; pi_l = po_l; po_l = ts;
        ts = ai_h; ai_h = ao_h; ao_h = ts;
        ts = ai_l; ai_l = ao_l; ao_l = ts;
    }
}

// Round 5
// 1036.511 us; speedup vs baseline: 1.6068x; 1.6068x over previous
//
#include <hip/hip_runtime.h>
#include <math.h>

#define H 256
#define G3 768        // 3*H
#define BB 512
#define AA 4
#define EE 10
#define RP (BB*AA*EE) // 20480 physical rows
#define RA (BB*AA)    // 2048 action rows
#define TT 10
#define NMV 2
#define STEPSC 0.05f

typedef __attribute__((ext_vector_type(8))) short short8;
typedef __attribute__((ext_vector_type(8))) _Float16 half8;
typedef __attribute__((ext_vector_type(4))) float f32x4;

#if defined(__has_builtin)
#  if __has_builtin(__builtin_amdgcn_global_load_lds)
#    define HAS_GLL 1
#  endif
#endif

__device__ __forceinline__ float sigmoid_(float x){ return 1.f/(1.f + __expf(-x)); }
__device__ __forceinline__ float tanh_(float x){
    float ax = fabsf(x);
    float e  = __expf(-2.f*ax);
    float t  = (1.f - e)/(1.f + e);
    return copysignf(t, x);
}
__device__ __forceinline__ float elu_(float x){ return x > 0.f ? x : (__expf(x) - 1.f); }

#define MFMA16(A,B,C) __builtin_amdgcn_mfma_f32_16x16x32_f16(A,B,C,0,0,0)

// 16B/lane global->LDS copy (async direct-to-LDS when available)
__device__ __forceinline__ void cp16(const void* g, void* l) {
#ifdef HAS_GLL
    __builtin_amdgcn_global_load_lds(
        (const __attribute__((address_space(1))) unsigned int*)g,
        (__attribute__((address_space(3))) unsigned int*)l, 16, 0, 0);
#else
    *(short8*)l = *(const short8*)g;
#endif
}

// split 8 consecutive fp32 into fp16 hi + fp16 lo fragments
__device__ __forceinline__ void split8(const float* p, half8& hi, half8& lo) {
    float4 v0 = *(const float4*)p;
    float4 v1 = *(const float4*)(p + 4);
    float f[8] = {v0.x, v0.y, v0.z, v0.w, v1.x, v1.y, v1.z, v1.w};
    #pragma unroll
    for (int e = 0; e < 8; e++) {
        _Float16 h = (_Float16)f[e];
        hi[e] = h;
        lo[e] = (_Float16)(f[e] - (float)h);
    }
}

// ---------------------------------------------------------------------------
// fp32 weight [Nout][ldsrc] -> fp16 in MFMA B-fragment order.
// i = ((chunk*8 + kc)*64 + lane)*8 + j ; row = chunk*16+(lane&15),
// k = kc*32 + (lane>>4)*8 + j.  Chunk = 16 output cols x 256 k = 4096 halfs.
// ---------------------------------------------------------------------------
__global__ void k_splitw(const float* __restrict__ src, _Float16* __restrict__ dst,
                         int n, int ldsrc)
{
    int i = blockIdx.x*256 + threadIdx.x;
    if (i < n) {
        int j  = i & 7;
        int l  = (i >> 3) & 63;
        int kc = (i >> 9) & 7;
        int c  = i >> 12;
        int row = c*16 + (l & 15);
        int k   = kc*32 + (l >> 4)*8 + j;
        dst[i] = (_Float16)src[(size_t)row*ldsrc + k];
    }
}

// gia_goal[ra][k] = b_ih_a[k] + sum_{j<3} goals[ra][j]*W_ih_a[k][256+j]
__global__ void k_gia_goal(const float* __restrict__ goals,
                           const float* __restrict__ Wiha,
                           const float* __restrict__ biha,
                           float* __restrict__ out)
{
    int idx = blockIdx.x*256 + threadIdx.x;
    int ra = idx / G3, k = idx % G3;
    float g0 = goals[ra*3+0], g1 = goals[ra*3+1], g2 = goals[ra*3+2];
    const float* w = Wiha + (size_t)k*259 + 256;
    out[idx] = biha[k] + g0*w[0] + g1*w[1] + g2*w[2];
}

// ---------------------------------------------------------------------------
// Physical GRU, v5: fp32 state, fp16 hi/lo A split in regs (2-term MFMA),
// plain-fp16 frag-ordered weights staged via global_load_lds (24 KB/slice).
// Block 256 thr = 4 waves x 16 rows = 64 rows; grid (RP/64, 4), NS=4 slices.
// ---------------------------------------------------------------------------
__global__ __launch_bounds__(256, 3)
void k_gru5p(const float* __restrict__ h_in, float* __restrict__ h_out,
             const _Float16* __restrict__ wf,
             const float* __restrict__ obs, const float* __restrict__ phys,
             const float* __restrict__ Wih, const float* __restrict__ bih,
             const float* __restrict__ bhh)
{
    __shared__ _Float16 Bw[3*4096];   // 24 KB

    const int tid = threadIdx.x;
    const int wv = tid >> 6, lane = tid & 63;
    const int quad = lane >> 4, l16 = lane & 15;
    const int m0 = blockIdx.x*64 + wv*16;

    half8 Ahi[8], Alo[8];
    const float* arow = h_in + (size_t)(m0 + l16)*H + quad*8;
    #pragma unroll
    for (int kc = 0; kc < 8; kc++) split8(arow + kc*32, Ahi[kc], Alo[kc]);

    // time-invariant per-row inputs for the inline input-gate computation
    float xv[4][5];
    #pragma unroll
    for (int r = 0; r < 4; r++) {
        int row = m0 + quad*4 + r;
        xv[r][0] = obs[(size_t)row*2+0];
        xv[r][1] = obs[(size_t)row*2+1];
        int b = row / (AA*EE), e = row % EE;
        const float* pp = phys + (size_t)(b*EE + e)*3;
        xv[r][2]=pp[0]; xv[r][3]=pp[1]; xv[r][4]=pp[2];
    }

    for (int s = 0; s < 4; s++) {
        const int cs = blockIdx.y*4 + s;
        if (s) __syncthreads();               // LDS reads of slice s-1 done
        #pragma unroll
        for (int g = 0; g < 3; g++) {
            const _Float16* src = wf + (size_t)(g*16 + cs)*4096;
            cp16(src + tid*8,        &Bw[g*4096 + tid*8]);
            cp16(src + 2048 + tid*8, &Bw[g*4096 + 2048 + tid*8]);
        }
        __syncthreads();                      // drains the async copies

        f32x4 acc[3];
        #pragma unroll
        for (int g = 0; g < 3; g++) acc[g] = (f32x4){0.f,0.f,0.f,0.f};

        #pragma unroll
        for (int kc = 0; kc < 8; kc++) {
            #pragma unroll
            for (int g = 0; g < 3; g++) {
                half8 b = *(const half8*)&Bw[(g*8 + kc)*512 + lane*8];
                acc[g] = MFMA16(Ahi[kc], b, acc[g]);
                acc[g] = MFMA16(Alo[kc], b, acc[g]);
            }
        }

        const int col = cs*16 + l16;
        const float bhr = bhh[col], bhz = bhh[256+col], bhn = bhh[512+col];
        const float br_ = bih[col], bz_ = bih[256+col], bn_ = bih[512+col];
        float wr[5], wz[5], wn[5];
        {
            const float* pr = Wih + (size_t)col*5;
            const float* pz = Wih + (size_t)(256+col)*5;
            const float* pn = Wih + (size_t)(512+col)*5;
            #pragma unroll
            for (int j = 0; j < 5; j++) { wr[j]=pr[j]; wz[j]=pz[j]; wn[j]=pn[j]; }
        }
        #pragma unroll
        for (int r = 0; r < 4; r++) {
            int row = m0 + quad*4 + r;
            float gr = br_, gz = bz_, gn = bn_;
            #pragma unroll
            for (int j = 0; j < 5; j++) {
                gr = fmaf(xv[r][j], wr[j], gr);
                gz = fmaf(xv[r][j], wz[j], gz);
                gn = fmaf(xv[r][j], wn[j], gn);
            }
            float hr = acc[0][r] + bhr;
            float hz = acc[1][r] + bhz;
            float hn = acc[2][r] + bhn;
            float rg = sigmoid_(gr + hr);
            float z  = sigmoid_(gz + hz);
            float n  = tanh_(gn + rg*hn);
            size_t idx = (size_t)row*H + col;
            h_out[idx] = (1.f - z)*n + z*h_in[idx];
        }
    }
}

// ---------------------------------------------------------------------------
// Action GRU with fused input-gate GEMM: gi = feat @ Wiha^T (+goal part) and
// gh = h_a @ Whha^T computed in the same K-loop (two B operands, two A sets).
// Block 64 rows; grid (RA/64, 4).
// ---------------------------------------------------------------------------
__global__ __launch_bounds__(256, 2)
void k_gru5a(const float* __restrict__ h_in, float* __restrict__ h_out,
             const float* __restrict__ feat,
             const _Float16* __restrict__ wfh, const _Float16* __restrict__ wfx,
             const float* __restrict__ gia, const float* __restrict__ bhh)
{
    __shared__ _Float16 Bh[3*4096];   // Whha slice
    __shared__ _Float16 Bx[3*4096];   // Wiha slice

    const int tid = threadIdx.x;
    const int wv = tid >> 6, lane = tid & 63;
    const int quad = lane >> 4, l16 = lane & 15;
    const int m0 = blockIdx.x*64 + wv*16;

    half8 Ahi[8], Alo[8], Xhi[8], Xlo[8];
    const float* arow = h_in + (size_t)(m0 + l16)*H + quad*8;
    const float* xrow = feat + (size_t)(m0 + l16)*H + quad*8;
    #pragma unroll
    for (int kc = 0; kc < 8; kc++) {
        split8(arow + kc*32, Ahi[kc], Alo[kc]);
        split8(xrow + kc*32, Xhi[kc], Xlo[kc]);
    }

    for (int s = 0; s < 4; s++) {
        const int cs = blockIdx.y*4 + s;
        if (s) __syncthreads();
        #pragma unroll
        for (int g = 0; g < 3; g++) {
            const _Float16* sh = wfh + (size_t)(g*16 + cs)*4096;
            const _Float16* sx = wfx + (size_t)(g*16 + cs)*4096;
            cp16(sh + tid*8,        &Bh[g*4096 + tid*8]);
            cp16(sh + 2048 + tid*8, &Bh[g*4096 + 2048 + tid*8]);
            cp16(sx + tid*8,        &Bx[g*4096 + tid*8]);
            cp16(sx + 2048 + tid*8, &Bx[g*4096 + 2048 + tid*8]);
        }
        __syncthreads();

        f32x4 ah[3], ax[3];
        #pragma unroll
        for (int g = 0; g < 3; g++) {
            ah[g] = (f32x4){0.f,0.f,0.f,0.f};
            ax[g] = (f32x4){0.f,0.f,0.f,0.f};
        }

        #pragma unroll
        for (int kc = 0; kc < 8; kc++) {
            #pragma unroll
            for (int g = 0; g < 3; g++) {
                half8 bh = *(const half8*)&Bh[(g*8 + kc)*512 + lane*8];
                half8 bx = *(const half8*)&Bx[(g*8 + kc)*512 + lane*8];
                ah[g] = MFMA16(Ahi[kc], bh, ah[g]);
                ah[g] = MFMA16(Alo[kc], bh, ah[g]);
                ax[g] = MFMA16(Xhi[kc], bx, ax[g]);
                ax[g] = MFMA16(Xlo[kc], bx, ax[g]);
            }
        }

        const int col = cs*16 + l16;
        const float bhr = bhh[col], bhz = bhh[256+col], bhn = bhh[512+col];
        #pragma unroll
        for (int r = 0; r < 4; r++) {
            int row = m0 + quad*4 + r;
            const float* gp = gia + (size_t)row*G3;
            float gr = gp[col]       + ax[0][r];
            float gz = gp[256+col]   + ax[1][r];
            float gn = gp[512+col]   + ax[2][r];
            float hr = ah[0][r] + bhr;
            float hz = ah[1][r] + bhz;
            float hn = ah[2][r] + bhn;
            float rg = sigmoid_(gr + hr);
            float z  = sigmoid_(gz + hz);
            float n  = tanh_(gn + rg*hn);
            size_t idx = (size_t)row*H + col;
            h_out[idx] = (1.f - z)*n + z*h_in[idx];
        }
    }
}

// ---------------------------------------------------------------------------
// FC layer: out[M x 256] = elu(x @ W^T + bias), fp32 in/out, fp16 weights.
// Block 64 rows; grid (M/64, 2), NS=4 -> 8 slices of 32 cols (16 KB each).
// ---------------------------------------------------------------------------
__global__ __launch_bounds__(256, 4)
void k_fc5(const float* __restrict__ x, float* __restrict__ out,
           const _Float16* __restrict__ wf, const float* __restrict__ bias)
{
    __shared__ _Float16 Bw[2*4096];   // 16 KB

    const int tid = threadIdx.x;
    const int wv = tid >> 6, lane = tid & 63;
    const int quad = lane >> 4, l16 = lane & 15;
    const int m0 = blockIdx.x*64 + wv*16;

    half8 Ahi[8], Alo[8];
    const float* arow = x + (size_t)(m0 + l16)*H + quad*8;
    #pragma unroll
    for (int kc = 0; kc < 8; kc++) split8(arow + kc*32, Ahi[kc], Alo[kc]);

    for (int s = 0; s < 4; s++) {
        const int cs = blockIdx.y*4 + s;    // 0..7
        if (s) __syncthreads();
        const _Float16* src = wf + (size_t)cs*8192;
        #pragma unroll
        for (int it = 0; it < 4; it++)
            cp16(src + it*2048 + tid*8, &Bw[it*2048 + tid*8]);
        __syncthreads();

        f32x4 acc[2];
        acc[0] = (f32x4){0.f,0.f,0.f,0.f};
        acc[1] = (f32x4){0.f,0.f,0.f,0.f};

        #pragma unroll
        for (int kc = 0; kc < 8; kc++) {
            #pragma unroll
            for (int ni = 0; ni < 2; ni++) {
                half8 b = *(const half8*)&Bw[ni*4096 + kc*512 + lane*8];
                acc[ni] = MFMA16(Ahi[kc], b, acc[ni]);
                acc[ni] = MFMA16(Alo[kc], b, acc[ni]);
            }
        }

        #pragma unroll
        for (int ni = 0; ni < 2; ni++) {
            const int col = cs*32 + ni*16 + l16;
            const float bs = bias[col];
            #pragma unroll
            for (int r = 0; r < 4; r++) {
                int row = m0 + quad*4 + r;
                out[(size_t)row*H + col] = elu_(acc[ni][r] + bs);
            }
        }
    }
}

// feat[ba][j] = max_e proc[ba*EE + e][j]
__global__ void k_pool(const float* __restrict__ proc, float* __restrict__ feat)
{
    int idx = blockIdx.x*256 + threadIdx.x;   // RA*H
    int ba = idx >> 8, j = idx & 255;
    const float* p = proc + (size_t)ba*EE*H + j;
    float m = p[0];
    #pragma unroll
    for (int e = 1; e < EE; e++) m = fmaxf(m, p[(size_t)e*H]);
    feat[idx] = m;
}

// out[row][v] = tanh(b_m2[v] + m1o[row] . W_m2[v]) * STEP
__global__ void k_m2(const float* __restrict__ X, const float* __restrict__ Wm2,
                     const float* __restrict__ bm2, float* __restrict__ out)
{
    int idx = blockIdx.x*256 + threadIdx.x;   // RA*NMV
    int row = idx >> 1, v = idx & 1;
    const float4* x = (const float4*)(X + (size_t)row*H);
    const float4* w = (const float4*)(Wm2 + (size_t)v*H);
    float s = bm2[v];
    #pragma unroll 4
    for (int i = 0; i < H/4; i++) {
        float4 a = x[i], b = w[i];
        s = fmaf(a.x, b.x, s); s = fmaf(a.y, b.y, s);
        s = fmaf(a.z, b.z, s); s = fmaf(a.w, b.w, s);
    }
    out[idx] = tanh_(s) * STEPSC;
}

extern "C" void kernel_launch(void* const* d_in, const int* in_sizes, int n_in,
                              void* d_out, int out_size, void* d_ws, size_t ws_size,
                              hipStream_t stream)
{
    const float* obs  = (const float*)d_in[0];
    const float* phys = (const float*)d_in[1];
    const float* goals= (const float*)d_in[2];
    const float* memp = (const float*)d_in[3];
    const float* mema = (const float*)d_in[4];
    const float* Wihp = (const float*)d_in[5];
    const float* Whhp = (const float*)d_in[6];
    const float* bihp = (const float*)d_in[7];
    const float* bhhp = (const float*)d_in[8];
    const float* Wfcp = (const float*)d_in[9];
    const float* bfcp = (const float*)d_in[10];
    const float* Wiha = (const float*)d_in[11];
    const float* Whha = (const float*)d_in[12];
    const float* biha = (const float*)d_in[13];
    const float* bhha = (const float*)d_in[14];
    const float* Wfca = (const float*)d_in[15];
    const float* bfca = (const float*)d_in[16];
    const float* Wm1  = (const float*)d_in[17];
    const float* bm1  = (const float*)d_in[18];
    const float* Wm2  = (const float*)d_in[19];
    const float* bm2  = (const float*)d_in[20];
    float* out = (float*)d_out;

    char* base = (char*)d_ws;
    size_t off = 0;
    auto alloc = [&](size_t bytes) -> char* {
        char* p = base + off;
        off += (bytes + 255) & ~(size_t)255;
        return p;
    };
    _Float16* wp_whh = (_Float16*)alloc((size_t)G3*H*2);
    _Float16* wp_wfc = (_Float16*)alloc((size_t)H*H*2);
    _Float16* wa_whh = (_Float16*)alloc((size_t)G3*H*2);
    _Float16* wa_wih = (_Float16*)alloc((size_t)G3*H*2);
    _Float16* wa_wfc = (_Float16*)alloc((size_t)H*H*2);
    _Float16* wa_wm1 = (_Float16*)alloc((size_t)H*H*2);
    float* gia_goal  = (float*)alloc((size_t)RA*G3*4);
    float* hp0  = (float*)alloc((size_t)RP*H*4);
    float* hp1  = (float*)alloc((size_t)RP*H*4);
    float* ha0  = (float*)alloc((size_t)RA*H*4);
    float* ha1  = (float*)alloc((size_t)RA*H*4);
    float* proc = (float*)alloc((size_t)RP*H*4);
    float* feat = (float*)alloc((size_t)RA*H*4);
    float* proca= (float*)alloc((size_t)RA*H*4);
    float* m1o  = (float*)alloc((size_t)RA*H*4);

    // --- pre-pass: weights -> fp16 fragment order; init states; goal gates ---
    k_splitw<<<(G3*H+255)/256, 256, 0, stream>>>(Whhp, wp_whh, G3*H, H);
    k_splitw<<<(H*H+255)/256, 256, 0, stream>>>(Wfcp, wp_wfc, H*H, H);
    k_splitw<<<(G3*H+255)/256, 256, 0, stream>>>(Whha, wa_whh, G3*H, H);
    k_splitw<<<(G3*H+255)/256, 256, 0, stream>>>(Wiha, wa_wih, G3*H, 259);
    k_splitw<<<(H*H+255)/256, 256, 0, stream>>>(Wfca, wa_wfc, H*H, H);
    k_splitw<<<(H*H+255)/256, 256, 0, stream>>>(Wm1,  wa_wm1, H*H, H);
    k_gia_goal<<<RA*G3/256, 256, 0, stream>>>(goals, Wiha, biha, gia_goal);
    hipMemcpyAsync(hp0, memp, sizeof(float)*(size_t)RP*H, hipMemcpyDeviceToDevice, stream);
    hipMemcpyAsync(ha0, mema, sizeof(float)*(size_t)RA*H, hipMemcpyDeviceToDevice, stream);

    float *pi = hp0, *po = hp1, *ai = ha0, *ao = ha1;
    for (int t = 0; t < TT; t++) {
        k_gru5p<<<dim3(RP/64, 4), 256, 0, stream>>>(pi, po, wp_whh,
                                                    obs, phys, Wihp, bihp, bhhp);
        k_fc5<<<dim3(RP/64, 2), 256, 0, stream>>>(po, proc, wp_wfc, bfcp);
        k_pool<<<RA*H/256, 256, 0, stream>>>(proc, feat);
        k_gru5a<<<dim3(RA/64, 4), 256, 0, stream>>>(ai, ao, feat,
                                                    wa_whh, wa_wih, gia_goal, bhha);
        k_fc5<<<dim3(RA/64, 2), 256, 0, stream>>>(ao, proca, wa_wfc, bfca);
        k_fc5<<<dim3(RA/64, 2), 256, 0, stream>>>(proca, m1o, wa_wm1, bm1);
        k_m2<<<RA*NMV/256, 256, 0, stream>>>(m1o, Wm2, bm2, out + (size_t)t*RA*NMV);

        float* tf;
        tf = pi; pi = po; po = tf;
        tf = ai; ai = ao; ao = tf;
    }
}

// Round 6
// 955.138 us; speedup vs baseline: 1.7437x; 1.0852x over previous
//
#include <hip/hip_runtime.h>
#include <math.h>

#define H 256
#define G3 768        // 3*H
#define BB 512
#define AA 4
#define EE 10
#define RP (BB*AA*EE) // 20480 physical rows
#define RA (BB*AA)    // 2048 action rows
#define TT 10
#define NMV 2
#define STEPSC 0.05f
#define AST 264       // LDS row stride in floats (4-way max aliasing, 16B aligned)

typedef __attribute__((ext_vector_type(8))) short short8;
typedef __attribute__((ext_vector_type(8))) _Float16 half8;
typedef __attribute__((ext_vector_type(4))) float f32x4;

#if defined(__has_builtin)
#  if __has_builtin(__builtin_amdgcn_global_load_lds)
#    define HAS_GLL 1
#  endif
#endif

__device__ __forceinline__ float sigmoid_(float x){ return 1.f/(1.f + __expf(-x)); }
__device__ __forceinline__ float tanh_(float x){
    float ax = fabsf(x);
    float e  = __expf(-2.f*ax);
    float t  = (1.f - e)/(1.f + e);
    return copysignf(t, x);
}
__device__ __forceinline__ float elu_(float x){ return x > 0.f ? x : (__expf(x) - 1.f); }

#define MFMA16(A,B,C) __builtin_amdgcn_mfma_f32_16x16x32_f16(A,B,C,0,0,0)

// 16B/lane global->LDS copy (async direct-to-LDS when available)
__device__ __forceinline__ void cp16(const void* g, void* l) {
#ifdef HAS_GLL
    __builtin_amdgcn_global_load_lds(
        (const __attribute__((address_space(1))) unsigned int*)g,
        (__attribute__((address_space(3))) unsigned int*)l, 16, 0, 0);
#else
    *(short8*)l = *(const short8*)g;
#endif
}

// split 8 consecutive fp32 into fp16 hi + fp16 lo fragments (works on LDS or global ptr)
__device__ __forceinline__ void split8(const float* p, half8& hi, half8& lo) {
    float4 v0 = *(const float4*)p;
    float4 v1 = *(const float4*)(p + 4);
    float f[8] = {v0.x, v0.y, v0.z, v0.w, v1.x, v1.y, v1.z, v1.w};
    #pragma unroll
    for (int e = 0; e < 8; e++) {
        _Float16 h = (_Float16)f[e];
        hi[e] = h;
        lo[e] = (_Float16)(f[e] - (float)h);
    }
}

// ---------------------------------------------------------------------------
// fp32 weight [Nout][ldsrc] -> fp16 in MFMA B-fragment order.
// i = ((chunk*8 + kc)*64 + lane)*8 + j ; row = chunk*16+(lane&15),
// k = kc*32 + (lane>>4)*8 + j.  Chunk = 16 output cols x 256 k = 4096 halfs.
// ---------------------------------------------------------------------------
__global__ void k_splitw(const float* __restrict__ src, _Float16* __restrict__ dst,
                         int n, int ldsrc)
{
    int i = blockIdx.x*256 + threadIdx.x;
    if (i < n) {
        int j  = i & 7;
        int l  = (i >> 3) & 63;
        int kc = (i >> 9) & 7;
        int c  = i >> 12;
        int row = c*16 + (l & 15);
        int k   = kc*32 + (l >> 4)*8 + j;
        dst[i] = (_Float16)src[(size_t)row*ldsrc + k];
    }
}

// gia_goal[ra][k] = b_ih_a[k] + sum_{j<3} goals[ra][j]*W_ih_a[k][256+j]
__global__ void k_gia_goal(const float* __restrict__ goals,
                           const float* __restrict__ Wiha,
                           const float* __restrict__ biha,
                           float* __restrict__ out)
{
    int idx = blockIdx.x*256 + threadIdx.x;
    int ra = idx / G3, k = idx % G3;
    float g0 = goals[ra*3+0], g1 = goals[ra*3+1], g2 = goals[ra*3+2];
    const float* w = Wiha + (size_t)k*259 + 256;
    out[idx] = biha[k] + g0*w[0] + g1*w[1] + g2*w[2];
}

// ---------------------------------------------------------------------------
// Physical GRU (unchanged from r5): fp32 state, fp16 hi/lo A split (2-term
// MFMA), fp16 frag-ordered weights staged via global_load_lds, 24 KB/slice.
// Block 256 thr = 4 waves x 16 rows = 64 rows; grid (RP/64, 4), NS=4 slices.
// ---------------------------------------------------------------------------
__global__ __launch_bounds__(256, 3)
void k_gru5p(const float* __restrict__ h_in, float* __restrict__ h_out,
             const _Float16* __restrict__ wf,
             const float* __restrict__ obs, const float* __restrict__ phys,
             const float* __restrict__ Wih, const float* __restrict__ bih,
             const float* __restrict__ bhh)
{
    __shared__ _Float16 Bw[3*4096];   // 24 KB

    const int tid = threadIdx.x;
    const int wv = tid >> 6, lane = tid & 63;
    const int quad = lane >> 4, l16 = lane & 15;
    const int m0 = blockIdx.x*64 + wv*16;

    half8 Ahi[8], Alo[8];
    const float* arow = h_in + (size_t)(m0 + l16)*H + quad*8;
    #pragma unroll
    for (int kc = 0; kc < 8; kc++) split8(arow + kc*32, Ahi[kc], Alo[kc]);

    float xv[4][5];
    #pragma unroll
    for (int r = 0; r < 4; r++) {
        int row = m0 + quad*4 + r;
        xv[r][0] = obs[(size_t)row*2+0];
        xv[r][1] = obs[(size_t)row*2+1];
        int b = row / (AA*EE), e = row % EE;
        const float* pp = phys + (size_t)(b*EE + e)*3;
        xv[r][2]=pp[0]; xv[r][3]=pp[1]; xv[r][4]=pp[2];
    }

    for (int s = 0; s < 4; s++) {
        const int cs = blockIdx.y*4 + s;
        if (s) __syncthreads();
        #pragma unroll
        for (int g = 0; g < 3; g++) {
            const _Float16* src = wf + (size_t)(g*16 + cs)*4096;
            cp16(src + tid*8,        &Bw[g*4096 + tid*8]);
            cp16(src + 2048 + tid*8, &Bw[g*4096 + 2048 + tid*8]);
        }
        __syncthreads();

        f32x4 acc[3];
        #pragma unroll
        for (int g = 0; g < 3; g++) acc[g] = (f32x4){0.f,0.f,0.f,0.f};

        #pragma unroll
        for (int kc = 0; kc < 8; kc++) {
            #pragma unroll
            for (int g = 0; g < 3; g++) {
                half8 b = *(const half8*)&Bw[(g*8 + kc)*512 + lane*8];
                acc[g] = MFMA16(Ahi[kc], b, acc[g]);
                acc[g] = MFMA16(Alo[kc], b, acc[g]);
            }
        }

        const int col = cs*16 + l16;
        const float bhr = bhh[col], bhz = bhh[256+col], bhn = bhh[512+col];
        const float br_ = bih[col], bz_ = bih[256+col], bn_ = bih[512+col];
        float wr[5], wz[5], wn[5];
        {
            const float* pr = Wih + (size_t)col*5;
            const float* pz = Wih + (size_t)(256+col)*5;
            const float* pn = Wih + (size_t)(512+col)*5;
            #pragma unroll
            for (int j = 0; j < 5; j++) { wr[j]=pr[j]; wz[j]=pz[j]; wn[j]=pn[j]; }
        }
        #pragma unroll
        for (int r = 0; r < 4; r++) {
            int row = m0 + quad*4 + r;
            float gr = br_, gz = bz_, gn = bn_;
            #pragma unroll
            for (int j = 0; j < 5; j++) {
                gr = fmaf(xv[r][j], wr[j], gr);
                gz = fmaf(xv[r][j], wz[j], gz);
                gn = fmaf(xv[r][j], wn[j], gn);
            }
            float hr = acc[0][r] + bhr;
            float hz = acc[1][r] + bhz;
            float hn = acc[2][r] + bhn;
            float rg = sigmoid_(gr + hr);
            float z  = sigmoid_(gz + hz);
            float n  = tanh_(gn + rg*hn);
            size_t idx = (size_t)row*H + col;
            h_out[idx] = (1.f - z)*n + z*h_in[idx];
        }
    }
}

// ---------------------------------------------------------------------------
// FC layer (physical): out[M x 256] = elu(x @ W^T + bias). NS=2, grid (M/64,4)
// -> 1280 blocks (r4 lesson: block count > slice reuse in this regime).
// ---------------------------------------------------------------------------
__global__ __launch_bounds__(256, 4)
void k_fc5(const float* __restrict__ x, float* __restrict__ out,
           const _Float16* __restrict__ wf, const float* __restrict__ bias)
{
    __shared__ _Float16 Bw[2*4096];   // 16 KB

    const int tid = threadIdx.x;
    const int wv = tid >> 6, lane = tid & 63;
    const int quad = lane >> 4, l16 = lane & 15;
    const int m0 = blockIdx.x*64 + wv*16;

    half8 Ahi[8], Alo[8];
    const float* arow = x + (size_t)(m0 + l16)*H + quad*8;
    #pragma unroll
    for (int kc = 0; kc < 8; kc++) split8(arow + kc*32, Ahi[kc], Alo[kc]);

    for (int s = 0; s < 2; s++) {
        const int cs = blockIdx.y*2 + s;    // 0..7
        if (s) __syncthreads();
        const _Float16* src = wf + (size_t)cs*8192;
        #pragma unroll
        for (int it = 0; it < 4; it++)
            cp16(src + it*2048 + tid*8, &Bw[it*2048 + tid*8]);
        __syncthreads();

        f32x4 acc[2];
        acc[0] = (f32x4){0.f,0.f,0.f,0.f};
        acc[1] = (f32x4){0.f,0.f,0.f,0.f};

        #pragma unroll
        for (int kc = 0; kc < 8; kc++) {
            #pragma unroll
            for (int ni = 0; ni < 2; ni++) {
                half8 b = *(const half8*)&Bw[ni*4096 + kc*512 + lane*8];
                acc[ni] = MFMA16(Ahi[kc], b, acc[ni]);
                acc[ni] = MFMA16(Alo[kc], b, acc[ni]);
            }
        }

        #pragma unroll
        for (int ni = 0; ni < 2; ni++) {
            const int col = cs*32 + ni*16 + l16;
            const float bs = bias[col];
            #pragma unroll
            for (int r = 0; r < 4; r++) {
                int row = m0 + quad*4 + r;
                out[(size_t)row*H + col] = elu_(acc[ni][r] + bs);
            }
        }
    }
}

// ---------------------------------------------------------------------------
// FUSED ACTION KERNEL: pool + action-GRU (with fused gi GEMM) + fc_a + m1 + m2.
// One block = 16 action rows x full 256 cols; 4 waves split cols per stage;
// intermediates in LDS (stride AST=264). Weights read from L2 in frag order
// (waves own disjoint cols -> no LDS-staging sharing to exploit).
// grid: RA/16 = 128 blocks.
// ---------------------------------------------------------------------------
__global__ __launch_bounds__(256, 1)
void k_act(const float* __restrict__ h_in, float* __restrict__ h_out,
           const float* __restrict__ proc,
           const _Float16* __restrict__ wfh,  // Whha frag
           const _Float16* __restrict__ wfx,  // Wiha frag (feat part)
           const _Float16* __restrict__ wfc,  // Wfca frag
           const _Float16* __restrict__ wm1,  // Wm1 frag
           const float* __restrict__ gia, const float* __restrict__ bhh,
           const float* __restrict__ bfc, const float* __restrict__ bm1,
           const float* __restrict__ Wm2, const float* __restrict__ bm2,
           float* __restrict__ out_t)
{
    __shared__ float sA[16*AST];   // feat -> proca
    __shared__ float sH[16*AST];   // h_in -> m1o
    __shared__ float sB[16*AST];   // h'

    const int tid = threadIdx.x;
    const int ra0 = blockIdx.x*16;
    const int wv = tid >> 6, lane = tid & 63;
    const int quad = lane >> 4, l16 = lane & 15;

    // ---- stage 0: pool (feat) + stage h_in ----
    for (int i = tid; i < 16*256; i += 256) {
        int r = i >> 8, c = i & 255;
        const float* p = proc + ((size_t)(ra0 + r)*EE)*H + c;
        float m = p[0];
        #pragma unroll
        for (int e = 1; e < EE; e++) m = fmaxf(m, p[(size_t)e*H]);
        sA[r*AST + c] = m;
        sH[r*AST + c] = h_in[(size_t)(ra0 + r)*H + c];
    }
    __syncthreads();

    // ---- stage 1: GRU (gh = h@Whha^T fused with gi_feat = feat@Wiha^T) ----
    half8 Ahi[8], Alo[8], Xhi[8], Xlo[8];
    #pragma unroll
    for (int kc = 0; kc < 8; kc++) {
        split8(&sH[l16*AST + quad*8 + kc*32], Ahi[kc], Alo[kc]);
        split8(&sA[l16*AST + quad*8 + kc*32], Xhi[kc], Xlo[kc]);
    }

    f32x4 ah[3][4], ax[3][4];
    #pragma unroll
    for (int g = 0; g < 3; g++)
        #pragma unroll
        for (int ch = 0; ch < 4; ch++) {
            ah[g][ch] = (f32x4){0.f,0.f,0.f,0.f};
            ax[g][ch] = (f32x4){0.f,0.f,0.f,0.f};
        }

    #pragma unroll
    for (int kc = 0; kc < 8; kc++) {
        #pragma unroll
        for (int ch = 0; ch < 4; ch++) {
            #pragma unroll
            for (int g = 0; g < 3; g++) {
                const size_t cg = (size_t)(g*16 + wv*4 + ch);
                half8 bh = *(const half8*)(wfh + (cg*8 + kc)*512 + lane*8);
                half8 bx = *(const half8*)(wfx + (cg*8 + kc)*512 + lane*8);
                ah[g][ch] = MFMA16(Ahi[kc], bh, ah[g][ch]);
                ah[g][ch] = MFMA16(Alo[kc], bh, ah[g][ch]);
                ax[g][ch] = MFMA16(Xhi[kc], bx, ax[g][ch]);
                ax[g][ch] = MFMA16(Xlo[kc], bx, ax[g][ch]);
            }
        }
    }

    #pragma unroll
    for (int ch = 0; ch < 4; ch++) {
        const int c = wv*64 + ch*16 + l16;
        const float bhr = bhh[c], bhz = bhh[256+c], bhn = bhh[512+c];
        #pragma unroll
        for (int reg = 0; reg < 4; reg++) {
            const int r = quad*4 + reg;
            const float* gp = gia + (size_t)(ra0 + r)*G3;
            float gr = gp[c]       + ax[0][ch][reg];
            float gz = gp[256+c]   + ax[1][ch][reg];
            float gn = gp[512+c]   + ax[2][ch][reg];
            float hr = ah[0][ch][reg] + bhr;
            float hz = ah[1][ch][reg] + bhz;
            float hn = ah[2][ch][reg] + bhn;
            float rg = sigmoid_(gr + hr);
            float z  = sigmoid_(gz + hz);
            float n  = tanh_(gn + rg*hn);
            float h  = (1.f - z)*n + z*sH[r*AST + c];
            sB[r*AST + c] = h;
            h_out[(size_t)(ra0 + r)*H + c] = h;
        }
    }
    __syncthreads();

    // ---- stage 2: proca = elu(h' @ Wfca^T + bfc) ----
    half8 Fhi[8], Flo[8];
    #pragma unroll
    for (int kc = 0; kc < 8; kc++)
        split8(&sB[l16*AST + quad*8 + kc*32], Fhi[kc], Flo[kc]);
    {
        f32x4 ac[4];
        #pragma unroll
        for (int ch = 0; ch < 4; ch++) ac[ch] = (f32x4){0.f,0.f,0.f,0.f};
        #pragma unroll
        for (int kc = 0; kc < 8; kc++)
            #pragma unroll
            for (int ch = 0; ch < 4; ch++) {
                const size_t cg = (size_t)(wv*4 + ch);
                half8 b = *(const half8*)(wfc + (cg*8 + kc)*512 + lane*8);
                ac[ch] = MFMA16(Fhi[kc], b, ac[ch]);
                ac[ch] = MFMA16(Flo[kc], b, ac[ch]);
            }
        __syncthreads();   // sA (feat) fully consumed by all waves' frag loads long ago; protect ordering anyway
        #pragma unroll
        for (int ch = 0; ch < 4; ch++) {
            const int c = wv*64 + ch*16 + l16;
            const float bs = bfc[c];
            #pragma unroll
            for (int reg = 0; reg < 4; reg++) {
                const int r = quad*4 + reg;
                sA[r*AST + c] = elu_(ac[ch][reg] + bs);
            }
        }
    }
    __syncthreads();

    // ---- stage 3: m1o = elu(proca @ Wm1^T + bm1) ----
    #pragma unroll
    for (int kc = 0; kc < 8; kc++)
        split8(&sA[l16*AST + quad*8 + kc*32], Fhi[kc], Flo[kc]);
    {
        f32x4 ac[4];
        #pragma unroll
        for (int ch = 0; ch < 4; ch++) ac[ch] = (f32x4){0.f,0.f,0.f,0.f};
        #pragma unroll
        for (int kc = 0; kc < 8; kc++)
            #pragma unroll
            for (int ch = 0; ch < 4; ch++) {
                const size_t cg = (size_t)(wv*4 + ch);
                half8 b = *(const half8*)(wm1 + (cg*8 + kc)*512 + lane*8);
                ac[ch] = MFMA16(Fhi[kc], b, ac[ch]);
                ac[ch] = MFMA16(Flo[kc], b, ac[ch]);
            }
        __syncthreads();   // all waves done reading sH (z*h in stage 1) and sA
        #pragma unroll
        for (int ch = 0; ch < 4; ch++) {
            const int c = wv*64 + ch*16 + l16;
            const float bs = bm1[c];
            #pragma unroll
            for (int reg = 0; reg < 4; reg++) {
                const int r = quad*4 + reg;
                sH[r*AST + c] = elu_(ac[ch][reg] + bs);
            }
        }
    }
    __syncthreads();

    // ---- stage 4: mv = tanh(m1o @ Wm2^T + bm2) * STEP ----
    if (tid < 32) {
        const int r = tid >> 1, v = tid & 1;
        const float* w = Wm2 + (size_t)v*H;
        float s = bm2[v];
        #pragma unroll 4
        for (int i = 0; i < H/4; i++) {
            float4 a = *(const float4*)&sH[r*AST + i*4];
            float4 b = *(const float4*)&w[i*4];
            s = fmaf(a.x, b.x, s); s = fmaf(a.y, b.y, s);
            s = fmaf(a.z, b.z, s); s = fmaf(a.w, b.w, s);
        }
        out_t[(size_t)(ra0 + r)*NMV + v] = tanh_(s)*STEPSC;
    }
}

extern "C" void kernel_launch(void* const* d_in, const int* in_sizes, int n_in,
                              void* d_out, int out_size, void* d_ws, size_t ws_size,
                              hipStream_t stream)
{
    const float* obs  = (const float*)d_in[0];
    const float* phys = (const float*)d_in[1];
    const float* goals= (const float*)d_in[2];
    const float* memp = (const float*)d_in[3];
    const float* mema = (const float*)d_in[4];
    const float* Wihp = (const float*)d_in[5];
    const float* Whhp = (const float*)d_in[6];
    const float* bihp = (const float*)d_in[7];
    const float* bhhp = (const float*)d_in[8];
    const float* Wfcp = (const float*)d_in[9];
    const float* bfcp = (const float*)d_in[10];
    const float* Wiha = (const float*)d_in[11];
    const float* Whha = (const float*)d_in[12];
    const float* biha = (const float*)d_in[13];
    const float* bhha = (const float*)d_in[14];
    const float* Wfca = (const float*)d_in[15];
    const float* bfca = (const float*)d_in[16];
    const float* Wm1  = (const float*)d_in[17];
    const float* bm1  = (const float*)d_in[18];
    const float* Wm2  = (const float*)d_in[19];
    const float* bm2  = (const float*)d_in[20];
    float* out = (float*)d_out;

    char* base = (char*)d_ws;
    size_t off = 0;
    auto alloc = [&](size_t bytes) -> char* {
        char* p = base + off;
        off += (bytes + 255) & ~(size_t)255;
        return p;
    };
    _Float16* wp_whh = (_Float16*)alloc((size_t)G3*H*2);
    _Float16* wp_wfc = (_Float16*)alloc((size_t)H*H*2);
    _Float16* wa_whh = (_Float16*)alloc((size_t)G3*H*2);
    _Float16* wa_wih = (_Float16*)alloc((size_t)G3*H*2);
    _Float16* wa_wfc = (_Float16*)alloc((size_t)H*H*2);
    _Float16* wa_wm1 = (_Float16*)alloc((size_t)H*H*2);
    float* gia_goal  = (float*)alloc((size_t)RA*G3*4);
    float* hp0  = (float*)alloc((size_t)RP*H*4);
    float* hp1  = (float*)alloc((size_t)RP*H*4);
    float* ha0  = (float*)alloc((size_t)RA*H*4);
    float* ha1  = (float*)alloc((size_t)RA*H*4);
    float* proc = (float*)alloc((size_t)RP*H*4);

    // --- pre-pass: weights -> fp16 fragment order; init states; goal gates ---
    k_splitw<<<(G3*H+255)/256, 256, 0, stream>>>(Whhp, wp_whh, G3*H, H);
    k_splitw<<<(H*H+255)/256, 256, 0, stream>>>(Wfcp, wp_wfc, H*H, H);
    k_splitw<<<(G3*H+255)/256, 256, 0, stream>>>(Whha, wa_whh, G3*H, H);
    k_splitw<<<(G3*H+255)/256, 256, 0, stream>>>(Wiha, wa_wih, G3*H, 259);
    k_splitw<<<(H*H+255)/256, 256, 0, stream>>>(Wfca, wa_wfc, H*H, H);
    k_splitw<<<(H*H+255)/256, 256, 0, stream>>>(Wm1,  wa_wm1, H*H, H);
    k_gia_goal<<<RA*G3/256, 256, 0, stream>>>(goals, Wiha, biha, gia_goal);
    hipMemcpyAsync(hp0, memp, sizeof(float)*(size_t)RP*H, hipMemcpyDeviceToDevice, stream);
    hipMemcpyAsync(ha0, mema, sizeof(float)*(size_t)RA*H, hipMemcpyDeviceToDevice, stream);

    float *pi = hp0, *po = hp1, *ai = ha0, *ao = ha1;
    for (int t = 0; t < TT; t++) {
        k_gru5p<<<dim3(RP/64, 4), 256, 0, stream>>>(pi, po, wp_whh,
                                                    obs, phys, Wihp, bihp, bhhp);
        k_fc5<<<dim3(RP/64, 4), 256, 0, stream>>>(po, proc, wp_wfc, bfcp);
        k_act<<<RA/16, 256, 0, stream>>>(ai, ao, proc,
                                         wa_whh, wa_wih, wa_wfc, wa_wm1,
                                         gia_goal, bhha, bfca, bm1, Wm2, bm2,
                                         out + (size_t)t*RA*NMV);

        float* tf;
        tf = pi; pi = po; po = tf;
        tf = ai; ai = ao; ao = tf;
    }
}